// Round 3
// baseline (212.514 us; speedup 1.0000x reference)
//
#include <hip/hip_runtime.h>

// Packed fp32: CDNA has full-rate v_pk_fma_f32 / v_pk_mul_f32. Express the
// recurrence on <2 x float> so the backend emits packed ops (2 elems/inst).
typedef float v2 __attribute__((ext_vector_type(2)));

__device__ __forceinline__ v2 splat(float s) { v2 r; r.x = s; r.y = s; return r; }
__device__ __forceinline__ v2 vfma(v2 a, v2 b, v2 c) {
    return __builtin_elementwise_fma(a, b, c);
}

// out = (tanh(100(x1-0.1)) - tanh(100(x1+0.1)) + 2)/2
//     = 1 + 1/(E+1) - 1/(E*e^-40 + 1),  E = e^{200(x1+0.1)}
// One v_exp_f32 + two v_rcp_f32. Saturates correctly for +-inf; NaN -> NaN.
__device__ __forceinline__ float band(float x1) {
    float E  = __builtin_amdgcn_exp2f(fmaf(288.539008f, x1, 28.8539008f)); // 200*log2e
    float Eu = E * 4.248354255291589e-18f;   // e^-40
    return 1.0f + __builtin_amdgcn_rcpf(E + 1.0f) - __builtin_amdgcn_rcpf(Eu + 1.0f);
}

// Two elements' trajectories per call, packed. w01[k] = splat(0.1*ws[k]).
__device__ __forceinline__ void traj2(v2& a0, v2& a1, const v2* __restrict__ w01) {
#pragma unroll
    for (int k = 0; k < 10; ++k) {
        v2 na0 = vfma(splat(-0.1f), a1, a0);      // x0 - 0.1*x1
        v2 s   = a0 * a0;
        v2 c   = s * a0;                          // x0^3
        v2 t1  = vfma(splat(0.1f), a0, a1);       // 0.1*x0 + x1
        v2 t2  = vfma(splat(-0.1f), c, t1);       // - 0.1*x0^3
        v2 na1 = vfma(w01[k], a1, t2);            // + (0.1*w)*x1
        a0 = na0; a1 = na1;
    }
}

// 8 elements/thread: 4 coalesced float4 loads at stride q, 4 float2 stores.
__global__ void __launch_bounds__(256)
dynsys_kernel(const float4* __restrict__ x, const float* __restrict__ ws,
              float2* __restrict__ out, int q) {
    int i = blockIdx.x * 256 + threadIdx.x;
    if (i >= q) return;

    v2 w01[10];
#pragma unroll
    for (int k = 0; k < 10; ++k) w01[k] = splat(0.1f * ws[k]);  // uniform -> s_load

    float4 va = x[i];
    float4 vb = x[i + q];
    float4 vc = x[i + 2 * q];
    float4 vd = x[i + 3 * q];

    v2 a0 = {va.x, va.z}, a1 = {va.y, va.w};
    v2 b0 = {vb.x, vb.z}, b1 = {vb.y, vb.w};
    v2 c0 = {vc.x, vc.z}, c1 = {vc.y, vc.w};
    v2 d0 = {vd.x, vd.z}, d1 = {vd.y, vd.w};

    traj2(a0, a1, w01);
    traj2(b0, b1, w01);
    traj2(c0, c1, w01);
    traj2(d0, d1, w01);

    out[i]         = make_float2(band(a1.x), band(a1.y));
    out[i + q]     = make_float2(band(b1.x), band(b1.y));
    out[i + 2 * q] = make_float2(band(c1.x), band(c1.y));
    out[i + 3 * q] = make_float2(band(d1.x), band(d1.y));
}

extern "C" void kernel_launch(void* const* d_in, const int* in_sizes, int n_in,
                              void* d_out, int out_size, void* d_ws, size_t ws_size,
                              hipStream_t stream) {
    const float4* x  = (const float4*)d_in[0];   // [B,2] f32 = B/2 float4s
    const float*  ws = (const float*)d_in[1];    // [10] f32
    float2* out = (float2*)d_out;                // [B] f32 = B/2 float2s

    int n4 = in_sizes[0] / 4;                    // float4 count = B/2
    int q  = n4 / 4;                             // 4 float4s per thread
    int blocks = (q + 255) / 256;
    dynsys_kernel<<<blocks, 256, 0, stream>>>(x, ws, out, q);
}